// Round 3
// baseline (480.307 us; speedup 1.0000x reference)
//
#include <hip/hip_runtime.h>
#include <hip/hip_bf16.h>
#include <math.h>

// Problem constants
#define NN   2048
#define EE   32768
#define NS   32
#define NV   16
#define NB   8          // NUM_BASIS
#define DD   32
#define TT   32
#define LL   2
#define HRD  64
#define NWW  3072
#define PI_F 3.14159265358979323846f

// scales
#define SC_SCS (1.0f/32.0f)                 // 1/sqrt(NS*D)
#define SC_SCV 0.04419417382415922f         // 1/sqrt(NV*D)=1/sqrt(512)
#define SC_L1S 0.17677669529663687f         // 1/sqrt(32)
#define SC_L1V 0.25f                        // 1/sqrt(16)
#define SC_R1  0.25f                        // 1/sqrt(2B)
#define SC_R2  0.125f                       // 1/sqrt(HR)
#define SC_ES  0.10206207261596575f         // 1/sqrt(96)
#define SC_EV  0.125f                       // 1/sqrt(64)
#define SC_AGG 0.25f                        // 1/sqrt(16)
#define SC_L2S 0.14433756729740643f         // 1/sqrt(48)
#define SC_L2V 0.25f
#define SC_SIS 0.17677669529663687f
#define SC_SIV 0.25f

typedef __attribute__((ext_vector_type(8))) short  short8;   // 8 bf16 (4 VGPRs)
typedef __attribute__((ext_vector_type(4))) float  floatx4;  // MFMA C/D

// ------------------------------------------------------------- K_setup
// block 0: LAPACK-convention Householder QR of W_uplift (16x2) -> Q
// blocks 1..64: per-type self-connection weights
// blocks 65..1600: W_r2 -> bf16 transposed [col][k]
// blocks 1601..1608: zero CSR counters
__global__ void k_setup(const float* __restrict__ Wup, float* __restrict__ Q,
                        const float* __restrict__ emb,
                        const float* __restrict__ Wscs, const float* __restrict__ Wscv,
                        float* __restrict__ WtS, float* __restrict__ WtV,
                        const float* __restrict__ Wr2, __hip_bfloat16* __restrict__ wr2t,
                        int* __restrict__ deg, int* __restrict__ cursor) {
    int b = blockIdx.x;
    if (b == 0) {
        if (threadIdx.x != 0) return;
        double A[16][2], tau[2];
        for (int i = 0; i < 16; ++i)
            for (int j = 0; j < 2; ++j) A[i][j] = (double)Wup[i*2 + j];
        for (int j = 0; j < 2; ++j) {
            double alpha = A[j][j];
            double xn2 = 0.0;
            for (int i = j + 1; i < 16; ++i) xn2 += A[i][j]*A[i][j];
            if (xn2 == 0.0) {
                tau[j] = 0.0;
            } else {
                double nrm  = sqrt(alpha*alpha + xn2);
                double beta = (alpha >= 0.0) ? -nrm : nrm;
                tau[j] = (beta - alpha) / beta;
                double s = 1.0 / (alpha - beta);
                for (int i = j + 1; i < 16; ++i) A[i][j] *= s;
                A[j][j] = beta;
            }
            for (int k = j + 1; k < 2; ++k) {
                double w = A[j][k];
                for (int i = j + 1; i < 16; ++i) w += A[i][j]*A[i][k];
                w *= tau[j];
                A[j][k] -= w;
                for (int i = j + 1; i < 16; ++i) A[i][k] -= A[i][j]*w;
            }
        }
        double Qm[16][2];
        for (int i = 0; i < 16; ++i)
            for (int j = 0; j < 2; ++j) Qm[i][j] = (i == j) ? 1.0 : 0.0;
        for (int j = 1; j >= 0; --j) {
            for (int k = 0; k < 2; ++k) {
                double w = Qm[j][k];
                for (int i = j + 1; i < 16; ++i) w += A[i][j]*Qm[i][k];
                w *= tau[j];
                Qm[j][k] -= w;
                for (int i = j + 1; i < 16; ++i) Qm[i][k] -= A[i][j]*w;
            }
        }
        for (int i = 0; i < 16; ++i)
            for (int j = 0; j < 2; ++j) Q[i*2 + j] = (float)Qm[i][j];
    } else if (b <= 64) {
        int lt = b - 1;
        int l = lt >> 5, t = lt & 31;
        __shared__ float es[32];
        if (threadIdx.x < 32) es[threadIdx.x] = emb[t*DD + threadIdx.x];
        __syncthreads();
        const float* Ws = Wscs + (size_t)l*NS*DD*48;
        float* oS = WtS + (size_t)(l*TT + t)*NS*48;
        for (int idx = threadIdx.x; idx < NS*48; idx += 256) {
            int i = idx / 48, j = idx % 48;
            float acc = 0.f;
            for (int a = 0; a < 32; ++a) acc += es[a]*Ws[(i*DD + a)*48 + j];
            oS[idx] = acc;
        }
        const float* Wv = Wscv + (size_t)l*NV*DD*NV;
        float* oV = WtV + (size_t)(l*TT + t)*NV*NV;
        for (int idx = threadIdx.x; idx < NV*NV; idx += 256) {
            int c = idx / 16, j = idx % 16;
            float acc = 0.f;
            for (int a = 0; a < 32; ++a) acc += es[a]*Wv[(c*DD + a)*NV + j];
            oV[idx] = acc;
        }
    } else if (b <= 1600) {
        int idx = (b - 65)*256 + threadIdx.x;      // L*64*3072 total
        int l = idx / (HRD*NWW);
        int r = idx - l*(HRD*NWW);
        int k = r / NWW;
        int c = r - k*NWW;
        wr2t[((size_t)l*NWW + c)*HRD + k] = __float2bfloat16(Wr2[idx]);
    } else {
        int i = (b - 1601)*256 + threadIdx.x;
        if (i < NN) { deg[i] = 0; cursor[i] = 0; }
    }
}

// --------------------------------------------------------------- CSR build
__global__ void k_hist(const int* __restrict__ edst, int* __restrict__ deg) {
    int e = blockIdx.x*256 + threadIdx.x;
    atomicAdd(&deg[edst[e]], 1);
}

__global__ void k_scan(const int* __restrict__ deg, int* __restrict__ row_ptr) {
    __shared__ int part[256];
    __shared__ int psc[256];
    int t = threadIdx.x;
    int loc[8]; int s = 0;
    for (int k = 0; k < 8; ++k) { loc[k] = deg[t*8 + k]; s += loc[k]; }
    part[t] = s;
    __syncthreads();
    if (t == 0) { int run = 0; for (int i = 0; i < 256; ++i) { psc[i] = run; run += part[i]; } }
    __syncthreads();
    int off = psc[t];
    for (int k = 0; k < 8; ++k) { row_ptr[t*8 + k] = off; off += loc[k]; }
    if (t == 255) row_ptr[2048] = off;
}

// blocks 0..127: fill invperm + pre-permuted src/dst; blocks 128..135: init y
__global__ void k_fill(const int* __restrict__ esrc, const int* __restrict__ edst,
                       const int* __restrict__ row_ptr, int* __restrict__ cursor,
                       int* __restrict__ invperm, int* __restrict__ srcs, int* __restrict__ dsts,
                       const float* __restrict__ xin, const float* __restrict__ Q,
                       float* __restrict__ ys0, float* __restrict__ yv0,
                       float* __restrict__ ys1, float* __restrict__ yv1,
                       float* __restrict__ xcur) {
    if (blockIdx.x < 128) {
        int e = blockIdx.x*256 + threadIdx.x;
        int d = edst[e];
        int pos = atomicAdd(&cursor[d], 1);
        int p = row_ptr[d] + pos;
        invperm[e] = p;
        srcs[p] = esrc[e];
        dsts[p] = d;
    } else {
        int n = (blockIdx.x - 128)*256 + threadIdx.x;  // exactly 2048
        float xl[6];
        for (int i = 0; i < 6; ++i) { xl[i] = xin[n*6 + i]; xcur[n*6 + i] = xl[i]; }
        for (int j = 0; j < 32; ++j) { ys0[n*32 + j] = 0.f; ys1[n*32 + j] = 0.f; }
        for (int c = 0; c < 16; ++c)
            for (int k = 0; k < 3; ++k) {
                float v = Q[c*2 + 0]*xl[k] + Q[c*2 + 1]*xl[3 + k];
                yv0[n*48 + c*3 + k] = v;
                yv1[n*48 + c*3 + k] = v;
            }
    }
}

// -------------------- K_pre: blocks 0..127 edge geometry+radial1 (permuted
// write), blocks 128..511 node lin1 + aggregator zeroing
__global__ void __launch_bounds__(256) k_pre(
        const float* __restrict__ xcur,
        const int* __restrict__ esrc, const int* __restrict__ edst,
        const int* __restrict__ invperm,
        const float* __restrict__ Wr1l,
        __hip_bfloat16* __restrict__ hrg, float* __restrict__ eag,
        const float* __restrict__ ys, const float* __restrict__ yv,
        const float* __restrict__ Wl1s, const float* __restrict__ Wl1v,
        float* __restrict__ s1, float* __restrict__ v1,
        float* __restrict__ nsb, float* __restrict__ nvb) {
    if (blockIdx.x < 128) {
        __shared__ float Wr1[16*64];
        for (int i = threadIdx.x; i < 16*64; i += 256) Wr1[i] = Wr1l[i];
        __syncthreads();
        int e = blockIdx.x*256 + threadIdx.x;
        int s = esrc[e], d = edst[e];
        int p = invperm[e];
        float ef[16];
        for (int m = 0; m < 2; ++m) {
            float v0 = xcur[s*6 + m*3 + 0] - xcur[d*6 + m*3 + 0];
            float v1_ = xcur[s*6 + m*3 + 1] - xcur[d*6 + m*3 + 1];
            float v2 = xcur[s*6 + m*3 + 2] - xcur[d*6 + m*3 + 2];
            float len = sqrtf(v0*v0 + v1_*v1_ + v2*v2 + 1e-12f);
            float inv = 1.0f/len;
            float theta = len*(PI_F/3.0f);
            float s1v = sinf(theta), c1v = cosf(theta);
            float sc  = 2.3094010767585034f*inv;  // sqrt(2/3)*sqrt(8)
            float sp = 0.f, scur = s1v, twoc = 2.f*c1v;
            for (int bq = 0; bq < 8; ++bq) {
                ef[m*8 + bq] = sc*scur;
                float sn = twoc*scur - sp;
                sp = scur; scur = sn;
            }
            float u = 2.0f*(len*(1.0f/3.0f) - 1.0f);
            float cut;
            if (u > 0.f) cut = 0.f;
            else if (u < -1.f) cut = 1.f;
            else cut = 0.5f*(1.0f - cosf(PI_F*u));
            float shs = 1.7320508075688772f*inv*cut;
            eag[p*6 + m*3 + 0] = shs*v0;
            eag[p*6 + m*3 + 1] = shs*v1_;
            eag[p*6 + m*3 + 2] = shs*v2;
        }
        for (int hh = 0; hh < 64; ++hh) {
            float z = 0.f;
            for (int f = 0; f < 16; ++f) z += ef[f]*Wr1[f*64 + hh];
            z *= SC_R1;
            hrg[(size_t)p*64 + hh] = __float2bfloat16(z/(1.0f + expf(-z)));
        }
    } else {
        int idx = (blockIdx.x - 128)*256 + threadIdx.x;  // exactly 2048*48
        int n = idx / 48, r = idx % 48;
        nsb[idx] = 0.f;
        nvb[idx] = 0.f;
        if (r < 32) {
            float acc = 0.f;
            for (int i = 0; i < 32; ++i) acc += ys[n*32 + i]*Wl1s[i*32 + r];
            s1[n*32 + r] = acc*SC_L1S;
        }
        int j = r/3, k = r - 3*j;
        float acc = 0.f;
        for (int c = 0; c < 16; ++c) acc += yv[n*48 + c*3 + k]*Wl1v[c*16 + j];
        v1[idx] = acc*SC_L1V;
    }
}

// ------------------------------ K_tp: fused radial2-MFMA + edge TP + reduce
// Edges arrive dst-sorted. 256 threads = 4 waves handle 64 edges; lane owns
// cols q*16+tc for edges 4*(tid>>4)+i (MFMA 16x16x32 C layout). Transposed
// LDS operands -> one broadcast ds_read_b128 per (q, operand). Block-local
// segmented reduction -> ~5 dst * 96 atomics per block.
__global__ void __launch_bounds__(256, 4) k_tp(
        const __hip_bfloat16* __restrict__ hrg, const float* __restrict__ eag,
        const float* __restrict__ s1g, const float* __restrict__ v1g,
        const int* __restrict__ srcs, const int* __restrict__ dsts,
        const __hip_bfloat16* __restrict__ wr2tl,
        float* __restrict__ nsb, float* __restrict__ nvb) {
    // phase-1 arrays aliased with phase-2 reduction buffer
    __shared__ __align__(16) char smem[30464];
    float (*s1t)[68]   = (float(*)[68])(smem);            //  8704 B
    float (*dots_t)[68]= (float(*)[68])(smem + 8704);     //  8704 B
    float (*v1t)[68]   = (float(*)[68])(smem + 17408);    // 13056 B
    float (*red)[100]  = (float(*)[100])(smem);           // 25600 B (phase 2)
    __shared__ float ea_s[64][8];
    __shared__ int   src_s[64];
    __shared__ int   dst_s[64];

    int tid = threadIdx.x;
    int wave = tid >> 6, lane = tid & 63;
    int te = tid >> 4, tc = tid & 15;
    int quad = lane >> 4;
    int ebase = blockIdx.x*64;
    int e0 = 4*te;   // == wave*16 + quad*4

    if (tid < 64) { src_s[tid] = srcs[ebase + tid]; dst_s[tid] = dsts[ebase + tid]; }
    for (int i = tid; i < 64*6; i += 256) ea_s[i/6][i%6] = eag[(size_t)ebase*6 + i];
    __syncthreads();
    for (int i = tid; i < 64*32; i += 256) {
        int e = i >> 5, s = i & 31;
        s1t[s][e] = s1g[src_s[e]*32 + s];
    }
    for (int i = tid; i < 64*48; i += 256) {
        int e = i/48, j = i%48;
        v1t[j][e] = v1g[src_s[e]*48 + j];
    }
    __syncthreads();
    for (int i = tid; i < 64*32; i += 256) {
        int cm = i >> 6, e = i & 63, c = cm >> 1, m = cm & 1;
        dots_t[cm][e] = v1t[c*3+0][e]*ea_s[e][m*3+0]
                      + v1t[c*3+1][e]*ea_s[e][m*3+1]
                      + v1t[c*3+2][e]*ea_s[e][m*3+2];
    }
    // ea for my 4 edges into registers (broadcast reads, free)
    float ear[4][6];
    #pragma unroll
    for (int i = 0; i < 4; ++i)
        #pragma unroll
        for (int k = 0; k < 6; ++k) ear[i][k] = ea_s[e0 + i][k];
    __syncthreads();

    // A fragments (chunk-invariant): lane holds hr[arow][quad*8 + j]
    const short* hr16 = (const short*)hrg;
    const short* w16  = (const short*)wr2tl;
    int arow = ebase + wave*16 + (lane & 15);
    short8 a_lo = *(const short8*)(hr16 + (size_t)arow*64 + quad*8);
    short8 a_hi = *(const short8*)(hr16 + (size_t)arow*64 + 32 + quad*8);

    float accES[4][3] = {{0,0,0},{0,0,0},{0,0,0},{0,0,0}};
    float accEV[4][3] = {{0,0,0},{0,0,0},{0,0,0},{0,0,0}};

    for (int ch = 0; ch < 48; ++ch) {
        floatx4 w4[4];
        #pragma unroll
        for (int q = 0; q < 4; ++q) {
            int col = ch*64 + q*16 + tc;
            const short* bp = w16 + (size_t)col*64 + quad*8;
            short8 b_lo = *(const short8*)(bp);
            short8 b_hi = *(const short8*)(bp + 32);
            floatx4 c = {0.f, 0.f, 0.f, 0.f};
            c = __builtin_amdgcn_mfma_f32_16x16x32_bf16(a_lo, b_lo, c, 0, 0, 0);
            c = __builtin_amdgcn_mfma_f32_16x16x32_bf16(a_hi, b_hi, c, 0, 0, 0);
            w4[q] = c;
        }

        if (ch < 16) {              // sv: sidx = 2ch+(q>>1), m = q&1
            #pragma unroll
            for (int q = 0; q < 4; ++q) {
                int m = q & 1;
                float4 sv = *(const float4*)&s1t[ch*2 + (q >> 1)][e0];
                #pragma unroll
                for (int i = 0; i < 4; ++i) {
                    float f = w4[q][i]*((&sv.x)[i]);
                    accEV[i][0] += f*ear[i][m*3 + 0];
                    accEV[i][1] += f*ear[i][m*3 + 1];
                    accEV[i][2] += f*ear[i][m*3 + 2];
                }
            }
        } else if (ch < 40) {       // vs: u = ch*4+q-64 in [0,96); c=u/6, v6=u%6
            #pragma unroll
            for (int q = 0; q < 4; ++q) {
                int u = ch*4 + q - 64;
                int c = (u*10923) >> 16;
                int v6 = u - 6*c;
                int m = (v6 >= 3) ? 1 : 0;
                int g = v6 - 3*m;
                float4 dv = *(const float4*)&dots_t[c*2 + m][e0];
                #pragma unroll
                for (int i = 0; i < 4; ++i)
                    accES[i][g] += w4[q][i]*((&dv.x)[i]);
            }
        } else {                    // vv: c = 2ch-80+(q>>1), m = q&1
            #pragma unroll
            for (int q = 0; q < 4; ++q) {
                int c = ch*2 - 80 + (q >> 1);
                int m = q & 1;
                float4 vx = *(const float4*)&v1t[c*3 + 0][e0];
                float4 vy = *(const float4*)&v1t[c*3 + 1][e0];
                float4 vz = *(const float4*)&v1t[c*3 + 2][e0];
                #pragma unroll
                for (int i = 0; i < 4; ++i) {
                    float ww = w4[q][i];
                    float a0 = ear[i][m*3 + 0], a1 = ear[i][m*3 + 1], a2 = ear[i][m*3 + 2];
                    float xv = (&vx.x)[i], yv = (&vy.x)[i], zv = (&vz.x)[i];
                    accEV[i][0] += ww*(yv*a2 - zv*a1);
                    accEV[i][1] += ww*(zv*a0 - xv*a2);
                    accEV[i][2] += ww*(xv*a1 - yv*a0);
                }
            }
        }
    }

    // ---- phase 2: block-local segmented reduction over sorted dst runs
    const float sES = SC_R2*SC_ES*SC_AGG;
    const float sEV = SC_R2*SC_EV*SC_AGG;
    __syncthreads();   // all phase-1 LDS reads done before overwrite
    #pragma unroll
    for (int i = 0; i < 4; ++i) {
        int pos = e0 + i;
        red[pos][tc]      = accES[i][0]*sES;
        red[pos][16 + tc] = accES[i][1]*sES;
        red[pos][32 + tc] = accES[i][2]*sES;
        red[pos][48 + tc*3 + 0] = accEV[i][0]*sEV;
        red[pos][48 + tc*3 + 1] = accEV[i][1]*sEV;
        red[pos][48 + tc*3 + 2] = accEV[i][2]*sEV;
    }
    __syncthreads();
    if (tid < 96) {
        int c = tid;
        float* base48 = (c < 48) ? nsb : nvb;
        int coff = (c < 48) ? c : (c - 48);
        float run = 0.f;
        int cur = dst_s[0];
        for (int pos = 0; pos < 64; ++pos) {
            int d = dst_s[pos];
            if (d != cur) {
                atomicAdd(&base48[cur*48 + coff], run);
                run = 0.f; cur = d;
            }
            run += red[pos][c];
        }
        atomicAdd(&base48[cur*48 + coff], run);
    }
}

// ----------------------- K6: node update (conv, gate, si, leapfrog, project)
__global__ void __launch_bounds__(256) k_nodepost(
        const float* __restrict__ ysC, const float* __restrict__ yvC,
        float* __restrict__ ysO, float* __restrict__ yvO,
        const float* __restrict__ nsb, const float* __restrict__ nvb,
        const int* __restrict__ nattr,
        const float* __restrict__ WtSl, const float* __restrict__ WtVl,
        const float* __restrict__ Wl2s, const float* __restrict__ Wl2v,
        const float* __restrict__ Wsis, const float* __restrict__ Wsiv,
        const float* __restrict__ harr, const float* __restrict__ mixarr, int l,
        float* __restrict__ xcur, float* __restrict__ xout2,
        const float* __restrict__ Qg) {
    int wave = threadIdx.x >> 6, lane = threadIdx.x & 63;
    int n = blockIdx.x*4 + wave;
    __shared__ float ys_s[4][32], yv_s[4][48], ns_s[4][48], nv_s[4][48];
    __shared__ float cs_s[4][48], nvo_s[4][48];

    if (lane < 32) ys_s[wave][lane] = ysC[n*32 + lane];
    if (lane < 48) {
        yv_s[wave][lane] = yvC[n*48 + lane];
        ns_s[wave][lane] = nsb[n*48 + lane];
        nv_s[wave][lane] = nvb[n*48 + lane];
    }
    __syncthreads();
    int t = nattr[n];
    const float* WtSn = WtSl + (size_t)t*NS*48;
    const float* WtVn = WtVl + (size_t)t*NV*NV;
    float hv = harr[l];
    float h2 = hv*hv, mx = mixarr[l];

    if (lane < 48) {
        float sc = 0.f, s2 = 0.f;
        for (int i = 0; i < 32; ++i) sc += ys_s[wave][i]*WtSn[i*48 + lane];
        for (int c = 0; c < 48; ++c) s2 += ns_s[wave][c]*Wl2s[c*48 + lane];
        cs_s[wave][lane] = sc*SC_SCS + s2*SC_L2S;
    }
    __syncthreads();
    if (lane < 48) {
        int j = lane/3, k = lane - 3*j;
        float scv = 0.f, v2 = 0.f, siv = 0.f;
        for (int c = 0; c < 16; ++c) {
            float yvv = yv_s[wave][c*3 + k];
            scv += yvv*WtVn[c*16 + j];
            v2  += nv_s[wave][c*3 + k]*Wl2v[c*16 + j];
            siv += yvv*Wsiv[c*16 + j];
        }
        float convv = scv*SC_SCV + v2*SC_L2V;
        siv *= SC_SIV;
        float gate = 1.f/(1.f + expf(-cs_s[wave][32 + j]));
        float gv = gate*convv;
        float nvnew = 2.f*yv_s[wave][lane] - yvO[n*48 + lane] + h2*(mx*gv + (mx - 1.f)*siv);
        nvo_s[wave][lane] = nvnew;
        yvO[n*48 + lane] = nvnew;
    }
    if (lane < 32) {
        float sis = 0.f;
        for (int i = 0; i < 32; ++i) sis += ys_s[wave][i]*Wsis[i*32 + lane];
        sis *= SC_SIS;
        float cs = cs_s[wave][lane];
        float gs = cs/(1.f + expf(-cs));
        float nsnew = 2.f*ys_s[wave][lane] - ysO[n*32 + lane] + h2*(mx*gs + (mx - 1.f)*sis);
        ysO[n*32 + lane] = nsnew;
    }
    __syncthreads();
    if (lane < 6) {
        int i = lane/3, k = lane - 3*(lane/3);
        float acc = 0.f;
        for (int c = 0; c < 16; ++c) acc += Qg[c*2 + i]*nvo_s[wave][c*3 + k];
        xcur[n*6 + lane]  = acc;
        xout2[n*6 + lane] = acc;
    }
}

// ---------------------------------------------------------------- launch
extern "C" void kernel_launch(void* const* d_in, const int* in_sizes, int n_in,
                              void* d_out, int out_size, void* d_ws, size_t ws_size,
                              hipStream_t stream) {
    const float* x_in  = (const float*)d_in[0];
    const int*   nattr = (const int*)  d_in[2];
    const int*   esrc  = (const int*)  d_in[3];
    const int*   edst  = (const int*)  d_in[4];
    const float* emb   = (const float*)d_in[5];
    const float* Wup   = (const float*)d_in[6];
    const float* Wscs  = (const float*)d_in[7];
    const float* Wscv  = (const float*)d_in[8];
    const float* Wl1s  = (const float*)d_in[9];
    const float* Wl1v  = (const float*)d_in[10];
    const float* Wr1   = (const float*)d_in[11];
    const float* Wr2   = (const float*)d_in[12];
    const float* Wl2s  = (const float*)d_in[13];
    const float* Wl2v  = (const float*)d_in[14];
    const float* Wsis  = (const float*)d_in[15];
    const float* Wsiv  = (const float*)d_in[16];
    const float* harr  = (const float*)d_in[17];
    const float* mixar = (const float*)d_in[18];
    float* out = (float*)d_out;

    float* ws = (float*)d_ws;
    size_t off = 0;
    float* Q    = ws + off; off += 32;
    float* WtS  = ws + off; off += (size_t)LL*TT*NS*48;     // 98304
    float* WtV  = ws + off; off += (size_t)LL*TT*NV*NV;     // 16384
    float* ys0  = ws + off; off += (size_t)NN*32;
    float* yv0  = ws + off; off += (size_t)NN*48;
    float* ys1  = ws + off; off += (size_t)NN*32;
    float* yv1  = ws + off; off += (size_t)NN*48;
    float* xcur = ws + off; off += (size_t)NN*6;
    float* s1   = ws + off; off += (size_t)NN*32;
    float* v1   = ws + off; off += (size_t)NN*48;
    float* nsb  = ws + off; off += (size_t)NN*48;
    float* nvb  = ws + off; off += (size_t)NN*48;
    float* eab  = ws + off; off += (size_t)EE*6;
    off = (off + 3) & ~(size_t)3;                           // 16B align
    __hip_bfloat16* hrb  = (__hip_bfloat16*)(ws + off); off += (size_t)EE*64/2;       // bf16
    __hip_bfloat16* wr2t = (__hip_bfloat16*)(ws + off); off += (size_t)LL*NWW*HRD/2;  // bf16
    int* deg     = (int*)(ws + off); off += NN;
    int* cursor  = (int*)(ws + off); off += NN;
    int* row_ptr = (int*)(ws + off); off += NN + 1;
    int* invperm = (int*)(ws + off); off += EE;
    int* srcs    = (int*)(ws + off); off += EE;
    int* dsts    = (int*)(ws + off); off += EE;

    k_setup<<<1609, 256, 0, stream>>>(Wup, Q, emb, Wscs, Wscv, WtS, WtV, Wr2, wr2t,
                                      deg, cursor);
    k_hist<<<EE/256, 256, 0, stream>>>(edst, deg);
    k_scan<<<1, 256, 0, stream>>>(deg, row_ptr);
    k_fill<<<136, 256, 0, stream>>>(esrc, edst, row_ptr, cursor, invperm, srcs, dsts,
                                    x_in, Q, ys0, yv0, ys1, yv1, xcur);

    float* curS = ys0; float* curV = yv0;
    float* oldS = ys1; float* oldV = yv1;
    for (int l = 0; l < LL; ++l) {
        k_pre<<<512, 256, 0, stream>>>(xcur, esrc, edst, invperm,
                                       Wr1 + (size_t)l*16*64, hrb, eab,
                                       curS, curV, Wl1s + (size_t)l*32*32,
                                       Wl1v + (size_t)l*16*16, s1, v1, nsb, nvb);
        k_tp<<<EE/64, 256, 0, stream>>>(hrb, eab, s1, v1, srcs, dsts,
                                        wr2t + (size_t)l*NWW*HRD, nsb, nvb);
        float* xo2 = (l == LL - 1) ? out : xcur;
        k_nodepost<<<NN/4, 256, 0, stream>>>(curS, curV, oldS, oldV, nsb, nvb, nattr,
                                             WtS + (size_t)l*TT*NS*48, WtV + (size_t)l*TT*NV*NV,
                                             Wl2s + (size_t)l*48*48, Wl2v + (size_t)l*16*16,
                                             Wsis + (size_t)l*32*32, Wsiv + (size_t)l*16*16,
                                             harr, mixar, l, xcur, xo2, Q);
        float* ts = curS; curS = oldS; oldS = ts;
        float* tv = curV; curV = oldV; oldV = tv;
    }
}

// Round 4
// 393.433 us; speedup vs baseline: 1.2208x; 1.2208x over previous
//
#include <hip/hip_runtime.h>
#include <hip/hip_bf16.h>
#include <math.h>

// Problem constants
#define NN   2048
#define EE   32768
#define NS   32
#define NV   16
#define NB   8          // NUM_BASIS
#define DD   32
#define TT   32
#define LL   2
#define HRD  64
#define NWW  3072
#define PI_F 3.14159265358979323846f

// scales
#define SC_SCS (1.0f/32.0f)                 // 1/sqrt(NS*D)
#define SC_SCV 0.04419417382415922f         // 1/sqrt(NV*D)=1/sqrt(512)
#define SC_L1S 0.17677669529663687f         // 1/sqrt(32)
#define SC_L1V 0.25f                        // 1/sqrt(16)
#define SC_R1  0.25f                        // 1/sqrt(2B)
#define SC_R2  0.125f                       // 1/sqrt(HR)
#define SC_ES  0.10206207261596575f         // 1/sqrt(96)
#define SC_EV  0.125f                       // 1/sqrt(64)
#define SC_AGG 0.25f                        // 1/sqrt(16)
#define SC_L2S 0.14433756729740643f         // 1/sqrt(48)
#define SC_L2V 0.25f
#define SC_SIS 0.17677669529663687f
#define SC_SIV 0.25f

typedef __attribute__((ext_vector_type(8))) short  short8;   // 8 bf16 (4 VGPRs)
typedef __attribute__((ext_vector_type(4))) float  floatx4;  // MFMA C/D

// ------------------------------------------------------------- K_setup
__global__ void k_setup(const float* __restrict__ Wup, float* __restrict__ Q,
                        const float* __restrict__ emb,
                        const float* __restrict__ Wscs, const float* __restrict__ Wscv,
                        float* __restrict__ WtS, float* __restrict__ WtV,
                        const float* __restrict__ Wr2, __hip_bfloat16* __restrict__ wr2t,
                        int* __restrict__ deg, int* __restrict__ cursor) {
    int b = blockIdx.x;
    if (b == 0) {
        if (threadIdx.x != 0) return;
        double A[16][2], tau[2];
        for (int i = 0; i < 16; ++i)
            for (int j = 0; j < 2; ++j) A[i][j] = (double)Wup[i*2 + j];
        for (int j = 0; j < 2; ++j) {
            double alpha = A[j][j];
            double xn2 = 0.0;
            for (int i = j + 1; i < 16; ++i) xn2 += A[i][j]*A[i][j];
            if (xn2 == 0.0) {
                tau[j] = 0.0;
            } else {
                double nrm  = sqrt(alpha*alpha + xn2);
                double beta = (alpha >= 0.0) ? -nrm : nrm;
                tau[j] = (beta - alpha) / beta;
                double s = 1.0 / (alpha - beta);
                for (int i = j + 1; i < 16; ++i) A[i][j] *= s;
                A[j][j] = beta;
            }
            for (int k = j + 1; k < 2; ++k) {
                double w = A[j][k];
                for (int i = j + 1; i < 16; ++i) w += A[i][j]*A[i][k];
                w *= tau[j];
                A[j][k] -= w;
                for (int i = j + 1; i < 16; ++i) A[i][k] -= A[i][j]*w;
            }
        }
        double Qm[16][2];
        for (int i = 0; i < 16; ++i)
            for (int j = 0; j < 2; ++j) Qm[i][j] = (i == j) ? 1.0 : 0.0;
        for (int j = 1; j >= 0; --j) {
            for (int k = 0; k < 2; ++k) {
                double w = Qm[j][k];
                for (int i = j + 1; i < 16; ++i) w += A[i][j]*Qm[i][k];
                w *= tau[j];
                Qm[j][k] -= w;
                for (int i = j + 1; i < 16; ++i) Qm[i][k] -= A[i][j]*w;
            }
        }
        for (int i = 0; i < 16; ++i)
            for (int j = 0; j < 2; ++j) Q[i*2 + j] = (float)Qm[i][j];
    } else if (b <= 64) {
        int lt = b - 1;
        int l = lt >> 5, t = lt & 31;
        __shared__ float es[32];
        if (threadIdx.x < 32) es[threadIdx.x] = emb[t*DD + threadIdx.x];
        __syncthreads();
        const float* Ws = Wscs + (size_t)l*NS*DD*48;
        float* oS = WtS + (size_t)(l*TT + t)*NS*48;
        for (int idx = threadIdx.x; idx < NS*48; idx += 256) {
            int i = idx / 48, j = idx % 48;
            float acc = 0.f;
            for (int a = 0; a < 32; ++a) acc += es[a]*Ws[(i*DD + a)*48 + j];
            oS[idx] = acc;
        }
        const float* Wv = Wscv + (size_t)l*NV*DD*NV;
        float* oV = WtV + (size_t)(l*TT + t)*NV*NV;
        for (int idx = threadIdx.x; idx < NV*NV; idx += 256) {
            int c = idx / 16, j = idx % 16;
            float acc = 0.f;
            for (int a = 0; a < 32; ++a) acc += es[a]*Wv[(c*DD + a)*NV + j];
            oV[idx] = acc;
        }
    } else if (b <= 1600) {
        int idx = (b - 65)*256 + threadIdx.x;      // L*64*3072 total
        int l = idx / (HRD*NWW);
        int r = idx - l*(HRD*NWW);
        int k = r / NWW;
        int c = r - k*NWW;
        wr2t[((size_t)l*NWW + c)*HRD + k] = __float2bfloat16(Wr2[idx]);
    } else {
        int i = (b - 1601)*256 + threadIdx.x;
        if (i < NN) { deg[i] = 0; cursor[i] = 0; }
    }
}

// --------------------------------------------------------------- CSR build
__global__ void k_hist(const int* __restrict__ edst, int* __restrict__ deg) {
    int e = blockIdx.x*256 + threadIdx.x;
    atomicAdd(&deg[edst[e]], 1);
}

__global__ void k_scan(const int* __restrict__ deg, int* __restrict__ row_ptr) {
    __shared__ int part[256];
    __shared__ int psc[256];
    int t = threadIdx.x;
    int loc[8]; int s = 0;
    for (int k = 0; k < 8; ++k) { loc[k] = deg[t*8 + k]; s += loc[k]; }
    part[t] = s;
    __syncthreads();
    if (t == 0) { int run = 0; for (int i = 0; i < 256; ++i) { psc[i] = run; run += part[i]; } }
    __syncthreads();
    int off = psc[t];
    for (int k = 0; k < 8; ++k) { row_ptr[t*8 + k] = off; off += loc[k]; }
    if (t == 255) row_ptr[2048] = off;
}

// blocks 0..127: fill invperm + pre-permuted src/dst; blocks 128..135: init y
__global__ void k_fill(const int* __restrict__ esrc, const int* __restrict__ edst,
                       const int* __restrict__ row_ptr, int* __restrict__ cursor,
                       int* __restrict__ invperm, int* __restrict__ srcs, int* __restrict__ dsts,
                       const float* __restrict__ xin, const float* __restrict__ Q,
                       float* __restrict__ ys0, float* __restrict__ yv0,
                       float* __restrict__ ys1, float* __restrict__ yv1,
                       float* __restrict__ xcur) {
    if (blockIdx.x < 128) {
        int e = blockIdx.x*256 + threadIdx.x;
        int d = edst[e];
        int pos = atomicAdd(&cursor[d], 1);
        int p = row_ptr[d] + pos;
        invperm[e] = p;
        srcs[p] = esrc[e];
        dsts[p] = d;
    } else {
        int n = (blockIdx.x - 128)*256 + threadIdx.x;  // exactly 2048
        float xl[6];
        for (int i = 0; i < 6; ++i) { xl[i] = xin[n*6 + i]; xcur[n*6 + i] = xl[i]; }
        for (int j = 0; j < 32; ++j) { ys0[n*32 + j] = 0.f; ys1[n*32 + j] = 0.f; }
        for (int c = 0; c < 16; ++c)
            for (int k = 0; k < 3; ++k) {
                float v = Q[c*2 + 0]*xl[k] + Q[c*2 + 1]*xl[3 + k];
                yv0[n*48 + c*3 + k] = v;
                yv1[n*48 + c*3 + k] = v;
            }
    }
}

// -------------------- K_pre: blocks 0..127 edge geometry+radial1 (permuted
// write), blocks 128..511 node lin1 + aggregator zeroing
__global__ void __launch_bounds__(256) k_pre(
        const float* __restrict__ xcur,
        const int* __restrict__ esrc, const int* __restrict__ edst,
        const int* __restrict__ invperm,
        const float* __restrict__ Wr1l,
        __hip_bfloat16* __restrict__ hrg, float* __restrict__ eag,
        const float* __restrict__ ys, const float* __restrict__ yv,
        const float* __restrict__ Wl1s, const float* __restrict__ Wl1v,
        float* __restrict__ s1, float* __restrict__ v1,
        float* __restrict__ nsb, float* __restrict__ nvb) {
    if (blockIdx.x < 128) {
        __shared__ float Wr1[16*64];
        for (int i = threadIdx.x; i < 16*64; i += 256) Wr1[i] = Wr1l[i];
        __syncthreads();
        int e = blockIdx.x*256 + threadIdx.x;
        int s = esrc[e], d = edst[e];
        int p = invperm[e];
        float ef[16];
        for (int m = 0; m < 2; ++m) {
            float v0 = xcur[s*6 + m*3 + 0] - xcur[d*6 + m*3 + 0];
            float v1_ = xcur[s*6 + m*3 + 1] - xcur[d*6 + m*3 + 1];
            float v2 = xcur[s*6 + m*3 + 2] - xcur[d*6 + m*3 + 2];
            float len = sqrtf(v0*v0 + v1_*v1_ + v2*v2 + 1e-12f);
            float inv = 1.0f/len;
            float theta = len*(PI_F/3.0f);
            float s1v = sinf(theta), c1v = cosf(theta);
            float sc  = 2.3094010767585034f*inv;  // sqrt(2/3)*sqrt(8)
            float sp = 0.f, scur = s1v, twoc = 2.f*c1v;
            for (int bq = 0; bq < 8; ++bq) {
                ef[m*8 + bq] = sc*scur;
                float sn = twoc*scur - sp;
                sp = scur; scur = sn;
            }
            float u = 2.0f*(len*(1.0f/3.0f) - 1.0f);
            float cut;
            if (u > 0.f) cut = 0.f;
            else if (u < -1.f) cut = 1.f;
            else cut = 0.5f*(1.0f - cosf(PI_F*u));
            float shs = 1.7320508075688772f*inv*cut;
            eag[p*6 + m*3 + 0] = shs*v0;
            eag[p*6 + m*3 + 1] = shs*v1_;
            eag[p*6 + m*3 + 2] = shs*v2;
        }
        for (int hh = 0; hh < 64; ++hh) {
            float z = 0.f;
            for (int f = 0; f < 16; ++f) z += ef[f]*Wr1[f*64 + hh];
            z *= SC_R1;
            hrg[(size_t)p*64 + hh] = __float2bfloat16(z/(1.0f + expf(-z)));
        }
    } else {
        int idx = (blockIdx.x - 128)*256 + threadIdx.x;  // exactly 2048*48
        int n = idx / 48, r = idx % 48;
        nsb[idx] = 0.f;
        nvb[idx] = 0.f;
        if (r < 32) {
            float acc = 0.f;
            for (int i = 0; i < 32; ++i) acc += ys[n*32 + i]*Wl1s[i*32 + r];
            s1[n*32 + r] = acc*SC_L1S;
        }
        int j = r/3, k = r - 3*j;
        float acc = 0.f;
        for (int c = 0; c < 16; ++c) acc += yv[n*48 + c*3 + k]*Wl1v[c*16 + j];
        v1[idx] = acc*SC_L1V;
    }
}

// ------------------------------ K_tp: fused radial2-MFMA + edge TP + reduce
// Edges arrive dst-sorted. Block-local segmented reduction; dst runs fully
// contained in this block's edge range are EXCLUSIVELY owned -> plain
// coalesced store (no RMW, no cross-XCD ping-pong); only the <=2 boundary
// runs per block use atomics (2-way contention max).
__global__ void __launch_bounds__(256, 4) k_tp(
        const __hip_bfloat16* __restrict__ hrg, const float* __restrict__ eag,
        const float* __restrict__ s1g, const float* __restrict__ v1g,
        const int* __restrict__ srcs, const int* __restrict__ dsts,
        const int* __restrict__ row_ptr,
        const __hip_bfloat16* __restrict__ wr2tl,
        float* __restrict__ nsb, float* __restrict__ nvb) {
    // phase-1 arrays aliased with phase-2 reduction buffer
    __shared__ __align__(16) char smem[30464];
    float (*s1t)[68]   = (float(*)[68])(smem);            //  8704 B
    float (*dots_t)[68]= (float(*)[68])(smem + 8704);     //  8704 B
    float (*v1t)[68]   = (float(*)[68])(smem + 17408);    // 13056 B
    float (*red)[100]  = (float(*)[100])(smem);           // 25600 B (phase 2)
    __shared__ float ea_s[64][8];
    __shared__ int   src_s[64];
    __shared__ int   dst_s[64];

    int tid = threadIdx.x;
    int wave = tid >> 6, lane = tid & 63;
    int te = tid >> 4, tc = tid & 15;
    int quad = lane >> 4;
    int ebase = blockIdx.x*64;
    int e0 = 4*te;   // == wave*16 + quad*4

    if (tid < 64) { src_s[tid] = srcs[ebase + tid]; dst_s[tid] = dsts[ebase + tid]; }
    for (int i = tid; i < 64*6; i += 256) ea_s[i/6][i%6] = eag[(size_t)ebase*6 + i];
    __syncthreads();
    for (int i = tid; i < 64*32; i += 256) {
        int e = i >> 5, s = i & 31;
        s1t[s][e] = s1g[src_s[e]*32 + s];
    }
    for (int i = tid; i < 64*48; i += 256) {
        int e = i/48, j = i%48;
        v1t[j][e] = v1g[src_s[e]*48 + j];
    }
    __syncthreads();
    for (int i = tid; i < 64*32; i += 256) {
        int cm = i >> 6, e = i & 63, c = cm >> 1, m = cm & 1;
        dots_t[cm][e] = v1t[c*3+0][e]*ea_s[e][m*3+0]
                      + v1t[c*3+1][e]*ea_s[e][m*3+1]
                      + v1t[c*3+2][e]*ea_s[e][m*3+2];
    }
    // ea for my 4 edges into registers (broadcast reads, free)
    float ear[4][6];
    #pragma unroll
    for (int i = 0; i < 4; ++i)
        #pragma unroll
        for (int k = 0; k < 6; ++k) ear[i][k] = ea_s[e0 + i][k];
    __syncthreads();

    // A fragments (chunk-invariant): lane holds hr[arow][quad*8 + j]
    const short* hr16 = (const short*)hrg;
    const short* w16  = (const short*)wr2tl;
    int arow = ebase + wave*16 + (lane & 15);
    short8 a_lo = *(const short8*)(hr16 + (size_t)arow*64 + quad*8);
    short8 a_hi = *(const short8*)(hr16 + (size_t)arow*64 + 32 + quad*8);

    float accES[4][3] = {{0,0,0},{0,0,0},{0,0,0},{0,0,0}};
    float accEV[4][3] = {{0,0,0},{0,0,0},{0,0,0},{0,0,0}};

    // region loops (no per-iteration region branch); unroll 2 lets the
    // compiler hoist two iterations' independent B-loads for latency cover
    #pragma unroll 2
    for (int ch = 0; ch < 16; ++ch) {          // sv: sidx = 2ch+(q>>1), m=q&1
        floatx4 w4[4];
        #pragma unroll
        for (int q = 0; q < 4; ++q) {
            int col = ch*64 + q*16 + tc;
            const short* bp = w16 + (size_t)col*64 + quad*8;
            short8 b_lo = *(const short8*)(bp);
            short8 b_hi = *(const short8*)(bp + 32);
            floatx4 c = {0.f, 0.f, 0.f, 0.f};
            c = __builtin_amdgcn_mfma_f32_16x16x32_bf16(a_lo, b_lo, c, 0, 0, 0);
            c = __builtin_amdgcn_mfma_f32_16x16x32_bf16(a_hi, b_hi, c, 0, 0, 0);
            w4[q] = c;
        }
        #pragma unroll
        for (int q = 0; q < 4; ++q) {
            int m = q & 1;
            float4 sv = *(const float4*)&s1t[ch*2 + (q >> 1)][e0];
            #pragma unroll
            for (int i = 0; i < 4; ++i) {
                float f = w4[q][i]*((&sv.x)[i]);
                accEV[i][0] += f*ear[i][m*3 + 0];
                accEV[i][1] += f*ear[i][m*3 + 1];
                accEV[i][2] += f*ear[i][m*3 + 2];
            }
        }
    }
    #pragma unroll 2
    for (int ch = 16; ch < 40; ++ch) {         // vs: u = ch*4+q-64 in [0,96)
        floatx4 w4[4];
        #pragma unroll
        for (int q = 0; q < 4; ++q) {
            int col = ch*64 + q*16 + tc;
            const short* bp = w16 + (size_t)col*64 + quad*8;
            short8 b_lo = *(const short8*)(bp);
            short8 b_hi = *(const short8*)(bp + 32);
            floatx4 c = {0.f, 0.f, 0.f, 0.f};
            c = __builtin_amdgcn_mfma_f32_16x16x32_bf16(a_lo, b_lo, c, 0, 0, 0);
            c = __builtin_amdgcn_mfma_f32_16x16x32_bf16(a_hi, b_hi, c, 0, 0, 0);
            w4[q] = c;
        }
        #pragma unroll
        for (int q = 0; q < 4; ++q) {
            int u = ch*4 + q - 64;
            int c = (u*10923) >> 16;
            int v6 = u - 6*c;
            int m = (v6 >= 3) ? 1 : 0;
            int g = v6 - 3*m;
            float4 dv = *(const float4*)&dots_t[c*2 + m][e0];
            #pragma unroll
            for (int i = 0; i < 4; ++i)
                accES[i][g] += w4[q][i]*((&dv.x)[i]);
        }
    }
    #pragma unroll 2
    for (int ch = 40; ch < 48; ++ch) {         // vv: c = 2ch-80+(q>>1), m=q&1
        floatx4 w4[4];
        #pragma unroll
        for (int q = 0; q < 4; ++q) {
            int col = ch*64 + q*16 + tc;
            const short* bp = w16 + (size_t)col*64 + quad*8;
            short8 b_lo = *(const short8*)(bp);
            short8 b_hi = *(const short8*)(bp + 32);
            floatx4 c = {0.f, 0.f, 0.f, 0.f};
            c = __builtin_amdgcn_mfma_f32_16x16x32_bf16(a_lo, b_lo, c, 0, 0, 0);
            c = __builtin_amdgcn_mfma_f32_16x16x32_bf16(a_hi, b_hi, c, 0, 0, 0);
            w4[q] = c;
        }
        #pragma unroll
        for (int q = 0; q < 4; ++q) {
            int c = ch*2 - 80 + (q >> 1);
            int m = q & 1;
            float4 vx = *(const float4*)&v1t[c*3 + 0][e0];
            float4 vy = *(const float4*)&v1t[c*3 + 1][e0];
            float4 vz = *(const float4*)&v1t[c*3 + 2][e0];
            #pragma unroll
            for (int i = 0; i < 4; ++i) {
                float ww = w4[q][i];
                float a0 = ear[i][m*3 + 0], a1 = ear[i][m*3 + 1], a2 = ear[i][m*3 + 2];
                float xv = (&vx.x)[i], yv = (&vy.x)[i], zv = (&vz.x)[i];
                accEV[i][0] += ww*(yv*a2 - zv*a1);
                accEV[i][1] += ww*(zv*a0 - xv*a2);
                accEV[i][2] += ww*(xv*a1 - yv*a0);
            }
        }
    }

    // ---- phase 2: block-local segmented reduction over sorted dst runs
    const float sES = SC_R2*SC_ES*SC_AGG;
    const float sEV = SC_R2*SC_EV*SC_AGG;
    __syncthreads();   // all phase-1 LDS reads done before overwrite
    #pragma unroll
    for (int i = 0; i < 4; ++i) {
        int pos = e0 + i;
        red[pos][tc]      = accES[i][0]*sES;
        red[pos][16 + tc] = accES[i][1]*sES;
        red[pos][32 + tc] = accES[i][2]*sES;
        red[pos][48 + tc*3 + 0] = accEV[i][0]*sEV;
        red[pos][48 + tc*3 + 1] = accEV[i][1]*sEV;
        red[pos][48 + tc*3 + 2] = accEV[i][2]*sEV;
    }
    __syncthreads();
    if (tid < 96) {
        int c = tid;
        float* base48 = (c < 48) ? nsb : nvb;
        int coff = (c < 48) ? c : (c - 48);
        float run = 0.f;
        int cur = dst_s[0];
        for (int pos = 0; pos < 64; ++pos) {
            int d = dst_s[pos];
            if (d != cur) {
                // flush run for dst `cur`
                if (row_ptr[cur] >= ebase && row_ptr[cur + 1] <= ebase + 64)
                    base48[cur*48 + coff] = run;              // exclusive
                else
                    atomicAdd(&base48[cur*48 + coff], run);   // boundary
                run = 0.f; cur = d;
            }
            run += red[pos][c];
        }
        if (row_ptr[cur] >= ebase && row_ptr[cur + 1] <= ebase + 64)
            base48[cur*48 + coff] = run;
        else
            atomicAdd(&base48[cur*48 + coff], run);
    }
}

// ----------------------- K6: node update (conv, gate, si, leapfrog, project)
__global__ void __launch_bounds__(256) k_nodepost(
        const float* __restrict__ ysC, const float* __restrict__ yvC,
        float* __restrict__ ysO, float* __restrict__ yvO,
        const float* __restrict__ nsb, const float* __restrict__ nvb,
        const int* __restrict__ nattr,
        const float* __restrict__ WtSl, const float* __restrict__ WtVl,
        const float* __restrict__ Wl2s, const float* __restrict__ Wl2v,
        const float* __restrict__ Wsis, const float* __restrict__ Wsiv,
        const float* __restrict__ harr, const float* __restrict__ mixarr, int l,
        float* __restrict__ xcur, float* __restrict__ xout2,
        const float* __restrict__ Qg) {
    int wave = threadIdx.x >> 6, lane = threadIdx.x & 63;
    int n = blockIdx.x*4 + wave;
    __shared__ float ys_s[4][32], yv_s[4][48], ns_s[4][48], nv_s[4][48];
    __shared__ float cs_s[4][48], nvo_s[4][48];

    if (lane < 32) ys_s[wave][lane] = ysC[n*32 + lane];
    if (lane < 48) {
        yv_s[wave][lane] = yvC[n*48 + lane];
        ns_s[wave][lane] = nsb[n*48 + lane];
        nv_s[wave][lane] = nvb[n*48 + lane];
    }
    __syncthreads();
    int t = nattr[n];
    const float* WtSn = WtSl + (size_t)t*NS*48;
    const float* WtVn = WtVl + (size_t)t*NV*NV;
    float hv = harr[l];
    float h2 = hv*hv, mx = mixarr[l];

    if (lane < 48) {
        float sc = 0.f, s2 = 0.f;
        for (int i = 0; i < 32; ++i) sc += ys_s[wave][i]*WtSn[i*48 + lane];
        for (int c = 0; c < 48; ++c) s2 += ns_s[wave][c]*Wl2s[c*48 + lane];
        cs_s[wave][lane] = sc*SC_SCS + s2*SC_L2S;
    }
    __syncthreads();
    if (lane < 48) {
        int j = lane/3, k = lane - 3*j;
        float scv = 0.f, v2 = 0.f, siv = 0.f;
        for (int c = 0; c < 16; ++c) {
            float yvv = yv_s[wave][c*3 + k];
            scv += yvv*WtVn[c*16 + j];
            v2  += nv_s[wave][c*3 + k]*Wl2v[c*16 + j];
            siv += yvv*Wsiv[c*16 + j];
        }
        float convv = scv*SC_SCV + v2*SC_L2V;
        siv *= SC_SIV;
        float gate = 1.f/(1.f + expf(-cs_s[wave][32 + j]));
        float gv = gate*convv;
        float nvnew = 2.f*yv_s[wave][lane] - yvO[n*48 + lane] + h2*(mx*gv + (mx - 1.f)*siv);
        nvo_s[wave][lane] = nvnew;
        yvO[n*48 + lane] = nvnew;
    }
    if (lane < 32) {
        float sis = 0.f;
        for (int i = 0; i < 32; ++i) sis += ys_s[wave][i]*Wsis[i*32 + lane];
        sis *= SC_SIS;
        float cs = cs_s[wave][lane];
        float gs = cs/(1.f + expf(-cs));
        float nsnew = 2.f*ys_s[wave][lane] - ysO[n*32 + lane] + h2*(mx*gs + (mx - 1.f)*sis);
        ysO[n*32 + lane] = nsnew;
    }
    __syncthreads();
    if (lane < 6) {
        int i = lane/3, k = lane - 3*(lane/3);
        float acc = 0.f;
        for (int c = 0; c < 16; ++c) acc += Qg[c*2 + i]*nvo_s[wave][c*3 + k];
        xcur[n*6 + lane]  = acc;
        xout2[n*6 + lane] = acc;
    }
}

// ---------------------------------------------------------------- launch
extern "C" void kernel_launch(void* const* d_in, const int* in_sizes, int n_in,
                              void* d_out, int out_size, void* d_ws, size_t ws_size,
                              hipStream_t stream) {
    const float* x_in  = (const float*)d_in[0];
    const int*   nattr = (const int*)  d_in[2];
    const int*   esrc  = (const int*)  d_in[3];
    const int*   edst  = (const int*)  d_in[4];
    const float* emb   = (const float*)d_in[5];
    const float* Wup   = (const float*)d_in[6];
    const float* Wscs  = (const float*)d_in[7];
    const float* Wscv  = (const float*)d_in[8];
    const float* Wl1s  = (const float*)d_in[9];
    const float* Wl1v  = (const float*)d_in[10];
    const float* Wr1   = (const float*)d_in[11];
    const float* Wr2   = (const float*)d_in[12];
    const float* Wl2s  = (const float*)d_in[13];
    const float* Wl2v  = (const float*)d_in[14];
    const float* Wsis  = (const float*)d_in[15];
    const float* Wsiv  = (const float*)d_in[16];
    const float* harr  = (const float*)d_in[17];
    const float* mixar = (const float*)d_in[18];
    float* out = (float*)d_out;

    float* ws = (float*)d_ws;
    size_t off = 0;
    float* Q    = ws + off; off += 32;
    float* WtS  = ws + off; off += (size_t)LL*TT*NS*48;     // 98304
    float* WtV  = ws + off; off += (size_t)LL*TT*NV*NV;     // 16384
    float* ys0  = ws + off; off += (size_t)NN*32;
    float* yv0  = ws + off; off += (size_t)NN*48;
    float* ys1  = ws + off; off += (size_t)NN*32;
    float* yv1  = ws + off; off += (size_t)NN*48;
    float* xcur = ws + off; off += (size_t)NN*6;
    float* s1   = ws + off; off += (size_t)NN*32;
    float* v1   = ws + off; off += (size_t)NN*48;
    float* nsb  = ws + off; off += (size_t)NN*48;           // 64B-aligned (all prior multiples of 16)
    float* nvb  = ws + off; off += (size_t)NN*48;
    float* eab  = ws + off; off += (size_t)EE*6;
    off = (off + 3) & ~(size_t)3;                           // 16B align
    __hip_bfloat16* hrb  = (__hip_bfloat16*)(ws + off); off += (size_t)EE*64/2;       // bf16
    __hip_bfloat16* wr2t = (__hip_bfloat16*)(ws + off); off += (size_t)LL*NWW*HRD/2;  // bf16
    int* deg     = (int*)(ws + off); off += NN;
    int* cursor  = (int*)(ws + off); off += NN;
    int* row_ptr = (int*)(ws + off); off += NN + 1;
    int* invperm = (int*)(ws + off); off += EE;
    int* srcs    = (int*)(ws + off); off += EE;
    int* dsts    = (int*)(ws + off); off += EE;

    k_setup<<<1609, 256, 0, stream>>>(Wup, Q, emb, Wscs, Wscv, WtS, WtV, Wr2, wr2t,
                                      deg, cursor);
    k_hist<<<EE/256, 256, 0, stream>>>(edst, deg);
    k_scan<<<1, 256, 0, stream>>>(deg, row_ptr);
    k_fill<<<136, 256, 0, stream>>>(esrc, edst, row_ptr, cursor, invperm, srcs, dsts,
                                    x_in, Q, ys0, yv0, ys1, yv1, xcur);

    float* curS = ys0; float* curV = yv0;
    float* oldS = ys1; float* oldV = yv1;
    for (int l = 0; l < LL; ++l) {
        k_pre<<<512, 256, 0, stream>>>(xcur, esrc, edst, invperm,
                                       Wr1 + (size_t)l*16*64, hrb, eab,
                                       curS, curV, Wl1s + (size_t)l*32*32,
                                       Wl1v + (size_t)l*16*16, s1, v1, nsb, nvb);
        k_tp<<<EE/64, 256, 0, stream>>>(hrb, eab, s1, v1, srcs, dsts, row_ptr,
                                        wr2t + (size_t)l*NWW*HRD, nsb, nvb);
        float* xo2 = (l == LL - 1) ? out : xcur;
        k_nodepost<<<NN/4, 256, 0, stream>>>(curS, curV, oldS, oldV, nsb, nvb, nattr,
                                             WtS + (size_t)l*TT*NS*48, WtV + (size_t)l*TT*NV*NV,
                                             Wl2s + (size_t)l*48*48, Wl2v + (size_t)l*16*16,
                                             Wsis + (size_t)l*32*32, Wsiv + (size_t)l*16*16,
                                             harr, mixar, l, xcur, xo2, Q);
        float* ts = curS; curS = oldS; oldS = ts;
        float* tv = curV; curV = oldV; oldV = tv;
    }
}